// Round 2
// baseline (198.473 us; speedup 1.0000x reference)
//
#include <hip/hip_runtime.h>
#include <hip/hip_bf16.h>

// CAM: per batch b (B=16):  a = x[b] viewed as [N=4096, C=256]
//   aTa  = a^T a            [C, C]
//   attn = softmax(aTa, -1)
//   y    = a · attn         [N, C]
//   out  = gamma * y + x
// Storage: fp32 (values bf16-quantized by harness). Internal: bf16 MFMA, fp32 accum.

#define BB 16
#define NN 4096   // H*W
#define CC 256

typedef __attribute__((ext_vector_type(4))) short short4v;
typedef __attribute__((ext_vector_type(8))) short short8v;
typedef __attribute__((ext_vector_type(4))) float floatx4;

__device__ __forceinline__ unsigned short f2bf(float f) {
    unsigned int u = __float_as_uint(f);
    u += 0x7fffu + ((u >> 16) & 1u);   // RNE (exact for already-bf16-grid values)
    return (unsigned short)(u >> 16);
}
__device__ __forceinline__ short4v cvt4(floatx4 v) {
    short4v r;
    r[0] = (short)f2bf(v[0]); r[1] = (short)f2bf(v[1]);
    r[2] = (short)f2bf(v[2]); r[3] = (short)f2bf(v[3]);
    return r;
}

// ---------------- K0: aT[b][c][n] = bf16(x[b][n][c]) --------------------
__global__ __launch_bounds__(256) void k_transpose(const float* __restrict__ x,
                                                   unsigned short* __restrict__ aT) {
    __shared__ unsigned short tile[64 * 68];   // [n_local][c_local], pitch 68
    const int b  = blockIdx.z;
    const int n0 = blockIdx.x * 64;
    const int c0 = blockIdx.y * 64;
    const int t  = threadIdx.x;
    const int q4 = (t & 15) * 4;   // 4-element quad offset
    const int tr = t >> 4;         // 0..15

    const float* xb = x + ((size_t)b * NN + n0) * CC + c0;
    for (int r = 0; r < 4; ++r) {
        int row = tr + 16 * r;     // n_local
        floatx4 v = *(const floatx4*)(xb + (size_t)row * CC + q4);
        *(short4v*)&tile[row * 68 + q4] = cvt4(v);
    }
    __syncthreads();
    unsigned short* aTb = aT + ((size_t)b * CC + c0) * NN + n0;
    for (int r = 0; r < 4; ++r) {
        int c = tr + 16 * r;       // c_local
        short4v v;
        v[0] = (short)tile[(q4 + 0) * 68 + c];
        v[1] = (short)tile[(q4 + 1) * 68 + c];
        v[2] = (short)tile[(q4 + 2) * 68 + c];
        v[3] = (short)tile[(q4 + 3) * 68 + c];
        *(short4v*)(aTb + (size_t)c * NN + q4) = v;
    }
}

// ---------------- K1: aTa[b] = a^T a  (M=N=256, K=4096) -----------------
__global__ __launch_bounds__(256) void k_gemm1(const unsigned short* __restrict__ aT,
                                               float* __restrict__ aTa) {
    __shared__ unsigned short Ap[64 * 72];   // [c_local][k], pitch 72
    __shared__ unsigned short Bp[64 * 72];
    const int b  = blockIdx.z;
    const int i0 = blockIdx.x * 64;
    const int j0 = blockIdx.y * 64;
    const int t  = threadIdx.x;
    const int w  = t >> 6, l = t & 63;
    const int wm = (w >> 1) * 32, wn = (w & 1) * 32;  // wave 2x2 over 64x64 tile
    const int lk = (l >> 4) * 8;                      // frag k offset within 32
    const int lm = l & 15;                            // frag m/n lane index
    const int sc = t >> 4;                            // staging row base 0..15
    const int sk = (t & 15) * 4;                      // staging k quad

    const unsigned short* Abase = aT + ((size_t)b * CC + i0) * NN;
    const unsigned short* Bbase = aT + ((size_t)b * CC + j0) * NN;

    floatx4 acc[2][2] = {};
    for (int k0 = 0; k0 < NN; k0 += 64) {
        for (int r = 0; r < 4; ++r) {
            int c = sc + 16 * r;
            *(short4v*)&Ap[c * 72 + sk] = *(const short4v*)(Abase + (size_t)c * NN + k0 + sk);
            *(short4v*)&Bp[c * 72 + sk] = *(const short4v*)(Bbase + (size_t)c * NN + k0 + sk);
        }
        __syncthreads();
        for (int ks = 0; ks < 64; ks += 32) {
            short8v af0 = *(const short8v*)&Ap[(wm + 0  + lm) * 72 + ks + lk];
            short8v af1 = *(const short8v*)&Ap[(wm + 16 + lm) * 72 + ks + lk];
            short8v bf0 = *(const short8v*)&Bp[(wn + 0  + lm) * 72 + ks + lk];
            short8v bf1 = *(const short8v*)&Bp[(wn + 16 + lm) * 72 + ks + lk];
            acc[0][0] = __builtin_amdgcn_mfma_f32_16x16x32_bf16(af0, bf0, acc[0][0], 0, 0, 0);
            acc[0][1] = __builtin_amdgcn_mfma_f32_16x16x32_bf16(af0, bf1, acc[0][1], 0, 0, 0);
            acc[1][0] = __builtin_amdgcn_mfma_f32_16x16x32_bf16(af1, bf0, acc[1][0], 0, 0, 0);
            acc[1][1] = __builtin_amdgcn_mfma_f32_16x16x32_bf16(af1, bf1, acc[1][1], 0, 0, 0);
        }
        __syncthreads();
    }
    const int orow = (l >> 4) * 4;   // C/D: row=(lane>>4)*4+r, col=lane&15
    for (int mt = 0; mt < 2; ++mt)
        for (int nt = 0; nt < 2; ++nt)
            for (int r = 0; r < 4; ++r) {
                int i = i0 + wm + mt * 16 + orow + r;
                int j = j0 + wn + nt * 16 + lm;
                aTa[((size_t)b * CC + i) * CC + j] = acc[mt][nt][r];
            }
}

// ---------------- K2: attn_T[b][j][i] = softmax_j(aTa[b][i][:]) ---------
__global__ __launch_bounds__(256) void k_softmax(const float* __restrict__ aTa,
                                                 unsigned short* __restrict__ attnT) {
    const int w = threadIdx.x >> 6;
    const int l = threadIdx.x & 63;
    const int row = blockIdx.x * 4 + w;   // global row 0..B*C-1
    const int b = row >> 8;
    const int i = row & 255;
    const float* p = aTa + ((size_t)b * CC + i) * CC;
    float v0 = p[l], v1 = p[l + 64], v2 = p[l + 128], v3 = p[l + 192];
    float m = fmaxf(fmaxf(v0, v1), fmaxf(v2, v3));
    for (int off = 32; off >= 1; off >>= 1) m = fmaxf(m, __shfl_xor(m, off, 64));
    v0 = __expf(v0 - m); v1 = __expf(v1 - m); v2 = __expf(v2 - m); v3 = __expf(v3 - m);
    float s = v0 + v1 + v2 + v3;
    for (int off = 32; off >= 1; off >>= 1) s += __shfl_xor(s, off, 64);
    float rs = 1.0f / s;
    unsigned short* o = attnT + (size_t)b * CC * CC + i;   // attnT[b][j][i]
    o[(size_t)(l +   0) * CC] = f2bf(v0 * rs);
    o[(size_t)(l +  64) * CC] = f2bf(v1 * rs);
    o[(size_t)(l + 128) * CC] = f2bf(v2 * rs);
    o[(size_t)(l + 192) * CC] = f2bf(v3 * rs);
}

// ---------------- K3: out = gamma * (a · attn) + x ----------------------
__global__ __launch_bounds__(256) void k_gemm2(const float* __restrict__ x,
                                               const unsigned short* __restrict__ attnT,
                                               const float* __restrict__ gamma,
                                               float* __restrict__ out) {
    __shared__ unsigned short At[64 * 72];
    __shared__ unsigned short Bt[64 * 72];
    const int b  = blockIdx.z;
    const int n0 = blockIdx.x * 64;   // spatial rows
    const int j0 = blockIdx.y * 64;   // output channels
    const int t  = threadIdx.x;
    const int w  = t >> 6, l = t & 63;
    const int wm = (w >> 1) * 32, wn = (w & 1) * 32;
    const int lk = (l >> 4) * 8, lm = l & 15;
    const int sc = t >> 4, sk = (t & 15) * 4;

    const float*          Abase = x + ((size_t)b * NN + n0) * CC;
    const unsigned short* Bbase = attnT + ((size_t)b * CC + j0) * CC;

    floatx4 acc[2][2] = {};
    for (int k0 = 0; k0 < CC; k0 += 64) {
        for (int r = 0; r < 4; ++r) {
            int c = sc + 16 * r;
            floatx4 av = *(const floatx4*)(Abase + (size_t)c * CC + k0 + sk);
            *(short4v*)&At[c * 72 + sk] = cvt4(av);
            *(short4v*)&Bt[c * 72 + sk] = *(const short4v*)(Bbase + (size_t)c * CC + k0 + sk);
        }
        __syncthreads();
        for (int ks = 0; ks < 64; ks += 32) {
            short8v af0 = *(const short8v*)&At[(wm + 0  + lm) * 72 + ks + lk];
            short8v af1 = *(const short8v*)&At[(wm + 16 + lm) * 72 + ks + lk];
            short8v bf0 = *(const short8v*)&Bt[(wn + 0  + lm) * 72 + ks + lk];
            short8v bf1 = *(const short8v*)&Bt[(wn + 16 + lm) * 72 + ks + lk];
            acc[0][0] = __builtin_amdgcn_mfma_f32_16x16x32_bf16(af0, bf0, acc[0][0], 0, 0, 0);
            acc[0][1] = __builtin_amdgcn_mfma_f32_16x16x32_bf16(af0, bf1, acc[0][1], 0, 0, 0);
            acc[1][0] = __builtin_amdgcn_mfma_f32_16x16x32_bf16(af1, bf0, acc[1][0], 0, 0, 0);
            acc[1][1] = __builtin_amdgcn_mfma_f32_16x16x32_bf16(af1, bf1, acc[1][1], 0, 0, 0);
        }
        __syncthreads();
    }
    const float g = gamma[0];
    const int orow = (l >> 4) * 4;
    for (int mt = 0; mt < 2; ++mt)
        for (int nt = 0; nt < 2; ++nt)
            for (int r = 0; r < 4; ++r) {
                int nr = n0 + wm + mt * 16 + orow + r;
                int j  = j0 + wn + nt * 16 + lm;
                size_t idx = ((size_t)b * NN + nr) * CC + j;
                out[idx] = g * acc[mt][nt][r] + x[idx];
            }
}

extern "C" void kernel_launch(void* const* d_in, const int* in_sizes, int n_in,
                              void* d_out, int out_size, void* d_ws, size_t ws_size,
                              hipStream_t stream) {
    const float* x     = (const float*)d_in[0];
    const float* gamma = (const float*)d_in[1];
    float* out = (float*)d_out;

    char* ws = (char*)d_ws;
    unsigned short* aT    = (unsigned short*)ws;                         // 16*256*4096*2 = 32 MB
    float*          aTa   = (float*)(ws + (size_t)BB * CC * NN * 2);     // 16*256*256*4  =  4 MB
    unsigned short* attnT = (unsigned short*)(ws + (size_t)BB * CC * NN * 2
                                                 + (size_t)BB * CC * CC * 4);  // 2 MB

    k_transpose<<<dim3(NN / 64, CC / 64, BB), 256, 0, stream>>>(x, aT);
    k_gemm1   <<<dim3(CC / 64, CC / 64, BB), 256, 0, stream>>>(aT, aTa);
    k_softmax <<<dim3(BB * CC / 4),          256, 0, stream>>>(aTa, attnT);
    k_gemm2   <<<dim3(NN / 64, CC / 64, BB), 256, 0, stream>>>(x, attnT, gamma, out);
}

// Round 3
// 187.305 us; speedup vs baseline: 1.0596x; 1.0596x over previous
//
#include <hip/hip_runtime.h>
#include <hip/hip_bf16.h>

// CAM: per batch b (B=16):  a = x[b] viewed as [N=4096, C=256]
//   aTa  = a^T a            [C, C]
//   attn = softmax(aTa, -1)
//   y    = a · attn         [N, C]
//   out  = gamma * y + x
// Storage: fp32 (values bf16-quantized by harness). Internal: bf16 MFMA, fp32 accum.

#define BB 16
#define NN 4096   // H*W
#define CC 256
#define SPLITK 8         // gemm1 split-K factor: 2048 blocks -> full occupancy
#define KCHUNK (NN / SPLITK)

typedef __attribute__((ext_vector_type(4))) short short4v;
typedef __attribute__((ext_vector_type(8))) short short8v;
typedef __attribute__((ext_vector_type(4))) float floatx4;

__device__ __forceinline__ unsigned short f2bf(float f) {
    unsigned int u = __float_as_uint(f);
    u += 0x7fffu + ((u >> 16) & 1u);   // RNE (exact for already-bf16-grid values)
    return (unsigned short)(u >> 16);
}
__device__ __forceinline__ short4v cvt4(floatx4 v) {
    short4v r;
    r[0] = (short)f2bf(v[0]); r[1] = (short)f2bf(v[1]);
    r[2] = (short)f2bf(v[2]); r[3] = (short)f2bf(v[3]);
    return r;
}

// ---------------- K0: aT[b][c][n] = bf16(x[b][n][c]) --------------------
__global__ __launch_bounds__(256) void k_transpose(const float* __restrict__ x,
                                                   unsigned short* __restrict__ aT) {
    __shared__ unsigned short tile[64 * 68];   // [n_local][c_local], pitch 68
    const int b  = blockIdx.z;
    const int n0 = blockIdx.x * 64;
    const int c0 = blockIdx.y * 64;
    const int t  = threadIdx.x;
    const int q4 = (t & 15) * 4;   // 4-element quad offset
    const int tr = t >> 4;         // 0..15

    const float* xb = x + ((size_t)b * NN + n0) * CC + c0;
    for (int r = 0; r < 4; ++r) {
        int row = tr + 16 * r;     // n_local
        floatx4 v = *(const floatx4*)(xb + (size_t)row * CC + q4);
        *(short4v*)&tile[row * 68 + q4] = cvt4(v);
    }
    __syncthreads();
    unsigned short* aTb = aT + ((size_t)b * CC + c0) * NN + n0;
    for (int r = 0; r < 4; ++r) {
        int c = tr + 16 * r;       // c_local
        short4v v;
        v[0] = (short)tile[(q4 + 0) * 68 + c];
        v[1] = (short)tile[(q4 + 1) * 68 + c];
        v[2] = (short)tile[(q4 + 2) * 68 + c];
        v[3] = (short)tile[(q4 + 3) * 68 + c];
        *(short4v*)(aTb + (size_t)c * NN + q4) = v;
    }
}

// ---------------- K1: aTa[b] += partial a^T a  (split-K) ----------------
// blockIdx.z = b * SPLITK + split; each block covers K range [split*KCHUNK, ...)
__global__ __launch_bounds__(256) void k_gemm1(const unsigned short* __restrict__ aT,
                                               float* __restrict__ aTa) {
    __shared__ unsigned short Ap[64 * 72];   // [c_local][k], pitch 72
    __shared__ unsigned short Bp[64 * 72];
    const int b     = blockIdx.z >> 3;       // SPLITK==8
    const int split = blockIdx.z & 7;
    const int i0 = blockIdx.x * 64;
    const int j0 = blockIdx.y * 64;
    const int t  = threadIdx.x;
    const int w  = t >> 6, l = t & 63;
    const int wm = (w >> 1) * 32, wn = (w & 1) * 32;  // wave 2x2 over 64x64 tile
    const int lk = (l >> 4) * 8;                      // frag k offset within 32
    const int lm = l & 15;                            // frag m/n lane index
    const int sc = t >> 4;                            // staging row base 0..15
    const int sk = (t & 15) * 4;                      // staging k quad

    const unsigned short* Abase = aT + ((size_t)b * CC + i0) * NN;
    const unsigned short* Bbase = aT + ((size_t)b * CC + j0) * NN;

    floatx4 acc[2][2] = {};
    const int kbeg = split * KCHUNK;
    for (int k0 = kbeg; k0 < kbeg + KCHUNK; k0 += 64) {
        for (int r = 0; r < 4; ++r) {
            int c = sc + 16 * r;
            *(short4v*)&Ap[c * 72 + sk] = *(const short4v*)(Abase + (size_t)c * NN + k0 + sk);
            *(short4v*)&Bp[c * 72 + sk] = *(const short4v*)(Bbase + (size_t)c * NN + k0 + sk);
        }
        __syncthreads();
        for (int ks = 0; ks < 64; ks += 32) {
            short8v af0 = *(const short8v*)&Ap[(wm + 0  + lm) * 72 + ks + lk];
            short8v af1 = *(const short8v*)&Ap[(wm + 16 + lm) * 72 + ks + lk];
            short8v bf0 = *(const short8v*)&Bp[(wn + 0  + lm) * 72 + ks + lk];
            short8v bf1 = *(const short8v*)&Bp[(wn + 16 + lm) * 72 + ks + lk];
            acc[0][0] = __builtin_amdgcn_mfma_f32_16x16x32_bf16(af0, bf0, acc[0][0], 0, 0, 0);
            acc[0][1] = __builtin_amdgcn_mfma_f32_16x16x32_bf16(af0, bf1, acc[0][1], 0, 0, 0);
            acc[1][0] = __builtin_amdgcn_mfma_f32_16x16x32_bf16(af1, bf0, acc[1][0], 0, 0, 0);
            acc[1][1] = __builtin_amdgcn_mfma_f32_16x16x32_bf16(af1, bf1, acc[1][1], 0, 0, 0);
        }
        __syncthreads();
    }
    const int orow = (l >> 4) * 4;   // C/D: row=(lane>>4)*4+r, col=lane&15
    for (int mt = 0; mt < 2; ++mt)
        for (int nt = 0; nt < 2; ++nt)
            for (int r = 0; r < 4; ++r) {
                int i = i0 + wm + mt * 16 + orow + r;
                int j = j0 + wn + nt * 16 + lm;
                unsafeAtomicAdd(&aTa[((size_t)b * CC + i) * CC + j], acc[mt][nt][r]);
            }
}

// ---------------- K2: attn_T[b][j][i] = softmax_j(aTa[b][i][:]) ---------
__global__ __launch_bounds__(256) void k_softmax(const float* __restrict__ aTa,
                                                 unsigned short* __restrict__ attnT) {
    const int w = threadIdx.x >> 6;
    const int l = threadIdx.x & 63;
    const int row = blockIdx.x * 4 + w;   // global row 0..B*C-1
    const int b = row >> 8;
    const int i = row & 255;
    const float* p = aTa + ((size_t)b * CC + i) * CC;
    float v0 = p[l], v1 = p[l + 64], v2 = p[l + 128], v3 = p[l + 192];
    float m = fmaxf(fmaxf(v0, v1), fmaxf(v2, v3));
    for (int off = 32; off >= 1; off >>= 1) m = fmaxf(m, __shfl_xor(m, off, 64));
    v0 = __expf(v0 - m); v1 = __expf(v1 - m); v2 = __expf(v2 - m); v3 = __expf(v3 - m);
    float s = v0 + v1 + v2 + v3;
    for (int off = 32; off >= 1; off >>= 1) s += __shfl_xor(s, off, 64);
    float rs = 1.0f / s;
    unsigned short* o = attnT + (size_t)b * CC * CC + i;   // attnT[b][j][i]
    o[(size_t)(l +   0) * CC] = f2bf(v0 * rs);
    o[(size_t)(l +  64) * CC] = f2bf(v1 * rs);
    o[(size_t)(l + 128) * CC] = f2bf(v2 * rs);
    o[(size_t)(l + 192) * CC] = f2bf(v3 * rs);
}

// ---------------- K3: out = gamma * (a · attn) + x ----------------------
__global__ __launch_bounds__(256) void k_gemm2(const float* __restrict__ x,
                                               const unsigned short* __restrict__ attnT,
                                               const float* __restrict__ gamma,
                                               float* __restrict__ out) {
    __shared__ unsigned short At[64 * 72];
    __shared__ unsigned short Bt[64 * 72];
    const int b  = blockIdx.z;
    const int n0 = blockIdx.x * 64;   // spatial rows
    const int j0 = blockIdx.y * 64;   // output channels
    const int t  = threadIdx.x;
    const int w  = t >> 6, l = t & 63;
    const int wm = (w >> 1) * 32, wn = (w & 1) * 32;
    const int lk = (l >> 4) * 8, lm = l & 15;
    const int sc = t >> 4, sk = (t & 15) * 4;

    const float*          Abase = x + ((size_t)b * NN + n0) * CC;
    const unsigned short* Bbase = attnT + ((size_t)b * CC + j0) * CC;

    floatx4 acc[2][2] = {};
    for (int k0 = 0; k0 < CC; k0 += 64) {
        for (int r = 0; r < 4; ++r) {
            int c = sc + 16 * r;
            floatx4 av = *(const floatx4*)(Abase + (size_t)c * CC + k0 + sk);
            *(short4v*)&At[c * 72 + sk] = cvt4(av);
            *(short4v*)&Bt[c * 72 + sk] = *(const short4v*)(Bbase + (size_t)c * CC + k0 + sk);
        }
        __syncthreads();
        for (int ks = 0; ks < 64; ks += 32) {
            short8v af0 = *(const short8v*)&At[(wm + 0  + lm) * 72 + ks + lk];
            short8v af1 = *(const short8v*)&At[(wm + 16 + lm) * 72 + ks + lk];
            short8v bf0 = *(const short8v*)&Bt[(wn + 0  + lm) * 72 + ks + lk];
            short8v bf1 = *(const short8v*)&Bt[(wn + 16 + lm) * 72 + ks + lk];
            acc[0][0] = __builtin_amdgcn_mfma_f32_16x16x32_bf16(af0, bf0, acc[0][0], 0, 0, 0);
            acc[0][1] = __builtin_amdgcn_mfma_f32_16x16x32_bf16(af0, bf1, acc[0][1], 0, 0, 0);
            acc[1][0] = __builtin_amdgcn_mfma_f32_16x16x32_bf16(af1, bf0, acc[1][0], 0, 0, 0);
            acc[1][1] = __builtin_amdgcn_mfma_f32_16x16x32_bf16(af1, bf1, acc[1][1], 0, 0, 0);
        }
        __syncthreads();
    }
    const float g = gamma[0];
    const int orow = (l >> 4) * 4;
    for (int mt = 0; mt < 2; ++mt)
        for (int nt = 0; nt < 2; ++nt)
            for (int r = 0; r < 4; ++r) {
                int nr = n0 + wm + mt * 16 + orow + r;
                int j  = j0 + wn + nt * 16 + lm;
                size_t idx = ((size_t)b * NN + nr) * CC + j;
                out[idx] = g * acc[mt][nt][r] + x[idx];
            }
}

extern "C" void kernel_launch(void* const* d_in, const int* in_sizes, int n_in,
                              void* d_out, int out_size, void* d_ws, size_t ws_size,
                              hipStream_t stream) {
    const float* x     = (const float*)d_in[0];
    const float* gamma = (const float*)d_in[1];
    float* out = (float*)d_out;

    char* ws = (char*)d_ws;
    unsigned short* aT    = (unsigned short*)ws;                         // 16*256*4096*2 = 32 MB
    float*          aTa   = (float*)(ws + (size_t)BB * CC * NN * 2);     // 16*256*256*4  =  4 MB
    unsigned short* attnT = (unsigned short*)(ws + (size_t)BB * CC * NN * 2
                                                 + (size_t)BB * CC * CC * 4);  // 2 MB

    // aTa is accumulated atomically by split-K gemm1 -> must start at zero
    // (harness poisons ws with 0xAA before every timed launch).
    hipMemsetAsync(aTa, 0, (size_t)BB * CC * CC * sizeof(float), stream);

    k_transpose<<<dim3(NN / 64, CC / 64, BB), 256, 0, stream>>>(x, aT);
    k_gemm1   <<<dim3(CC / 64, CC / 64, BB * SPLITK), 256, 0, stream>>>(aT, aTa);
    k_softmax <<<dim3(BB * CC / 4),          256, 0, stream>>>(aTa, attnT);
    k_gemm2   <<<dim3(NN / 64, CC / 64, BB), 256, 0, stream>>>(x, attnT, gamma, out);
}

// Round 4
// 180.260 us; speedup vs baseline: 1.1010x; 1.0391x over previous
//
#include <hip/hip_runtime.h>
#include <hip/hip_bf16.h>

// CAM: per batch b (B=16):  a = x[b] viewed as [N=4096, C=256]
//   aTa  = a^T a            [C, C]
//   attn = softmax(aTa, -1)
//   y    = a · attn         [N, C]
//   out  = gamma * y + x
// Storage: fp32 (values bf16-quantized by harness). Internal: bf16 MFMA, fp32 accum.
// gemm1 is split-K with per-split partial buffers (NO atomics — R3 showed the
// 8.4M-atomic epilogue serialized ~30us); softmax sums the partials.

#define BB 16
#define NN 4096   // H*W
#define CC 256
#define SPLITK 8
#define KCHUNK (NN / SPLITK)   // 512

typedef __attribute__((ext_vector_type(4))) short short4v;
typedef __attribute__((ext_vector_type(8))) short short8v;
typedef __attribute__((ext_vector_type(4))) float floatx4;

__device__ __forceinline__ unsigned short f2bf(float f) {
    unsigned int u = __float_as_uint(f);
    u += 0x7fffu + ((u >> 16) & 1u);   // RNE (exact for already-bf16-grid values)
    return (unsigned short)(u >> 16);
}
__device__ __forceinline__ short4v cvt4(floatx4 v) {
    short4v r;
    r[0] = (short)f2bf(v[0]); r[1] = (short)f2bf(v[1]);
    r[2] = (short)f2bf(v[2]); r[3] = (short)f2bf(v[3]);
    return r;
}

// ---------------- K0: aT[b][c][n] = bf16(x[b][n][c]) --------------------
__global__ __launch_bounds__(256) void k_transpose(const float* __restrict__ x,
                                                   unsigned short* __restrict__ aT) {
    __shared__ unsigned short tile[64 * 68];
    const int b  = blockIdx.z;
    const int n0 = blockIdx.x * 64;
    const int c0 = blockIdx.y * 64;
    const int t  = threadIdx.x;
    const int q4 = (t & 15) * 4;
    const int tr = t >> 4;

    const float* xb = x + ((size_t)b * NN + n0) * CC + c0;
    for (int r = 0; r < 4; ++r) {
        int row = tr + 16 * r;
        floatx4 v = *(const floatx4*)(xb + (size_t)row * CC + q4);
        *(short4v*)&tile[row * 68 + q4] = cvt4(v);
    }
    __syncthreads();
    unsigned short* aTb = aT + ((size_t)b * CC + c0) * NN + n0;
    for (int r = 0; r < 4; ++r) {
        int c = tr + 16 * r;
        short4v v;
        v[0] = (short)tile[(q4 + 0) * 68 + c];
        v[1] = (short)tile[(q4 + 1) * 68 + c];
        v[2] = (short)tile[(q4 + 2) * 68 + c];
        v[3] = (short)tile[(q4 + 3) * 68 + c];
        *(short4v*)(aTb + (size_t)c * NN + q4) = v;
    }
}

// ---------------- K1: part[split][b] = partial a^T a --------------------
// Block tile: 64 i-rows x ALL 256 j. grid (4, BB, SPLITK) = 512 blocks.
// Wave w owns j-slice [w*64, w*64+64): 4x4 accs, 8 ds_read_b128 : 16 MFMA.
__global__ __launch_bounds__(256) void k_gemm1(const unsigned short* __restrict__ aT,
                                               float* __restrict__ part) {
    __shared__ unsigned short Ap[64 * 72];    // [i_local][k]
    __shared__ unsigned short Bp[256 * 72];   // [j][k]
    const int i0    = blockIdx.x * 64;
    const int b     = blockIdx.y;
    const int split = blockIdx.z;
    const int t  = threadIdx.x;
    const int w  = t >> 6, l = t & 63;
    const int lk = (l >> 4) * 8;
    const int lm = l & 15;
    const int sc = t >> 4;            // 0..15
    const int sk = (t & 15) * 4;

    const unsigned short* Abase = aT + ((size_t)b * CC + i0) * NN;
    const unsigned short* Bbase = aT + (size_t)b * CC * NN;

    floatx4 acc[4][4] = {};
    const int kbeg = split * KCHUNK;
    for (int k0 = kbeg; k0 < kbeg + KCHUNK; k0 += 64) {
        #pragma unroll
        for (int r = 0; r < 4; ++r) {
            int i = sc + 16 * r;
            *(short4v*)&Ap[i * 72 + sk] = *(const short4v*)(Abase + (size_t)i * NN + k0 + sk);
        }
        #pragma unroll
        for (int r = 0; r < 16; ++r) {
            int j = sc + 16 * r;
            *(short4v*)&Bp[j * 72 + sk] = *(const short4v*)(Bbase + (size_t)j * NN + k0 + sk);
        }
        __syncthreads();
        #pragma unroll
        for (int ks = 0; ks < 64; ks += 32) {
            short8v af[4], bf[4];
            #pragma unroll
            for (int mt = 0; mt < 4; ++mt)
                af[mt] = *(const short8v*)&Ap[(mt * 16 + lm) * 72 + ks + lk];
            #pragma unroll
            for (int nt = 0; nt < 4; ++nt)
                bf[nt] = *(const short8v*)&Bp[(w * 64 + nt * 16 + lm) * 72 + ks + lk];
            #pragma unroll
            for (int mt = 0; mt < 4; ++mt)
                #pragma unroll
                for (int nt = 0; nt < 4; ++nt)
                    acc[mt][nt] = __builtin_amdgcn_mfma_f32_16x16x32_bf16(af[mt], bf[nt], acc[mt][nt], 0, 0, 0);
        }
        __syncthreads();
    }
    const int orow = (l >> 4) * 4;    // C/D: row=(lane>>4)*4+r, col=lane&15
    float* pout = part + ((size_t)(split * BB + b) * CC) * CC;
    #pragma unroll
    for (int mt = 0; mt < 4; ++mt)
        #pragma unroll
        for (int nt = 0; nt < 4; ++nt)
            #pragma unroll
            for (int r = 0; r < 4; ++r) {
                int i = i0 + mt * 16 + orow + r;
                int j = w * 64 + nt * 16 + lm;
                pout[(size_t)i * CC + j] = acc[mt][nt][r];
            }
}

// ---------------- K2: attn_T[b][j][i] = softmax over summed partials ----
__global__ __launch_bounds__(256) void k_softmax(const float* __restrict__ part,
                                                 unsigned short* __restrict__ attnT) {
    const int w = threadIdx.x >> 6;
    const int l = threadIdx.x & 63;
    const int row = blockIdx.x * 4 + w;   // 0..B*C-1
    const int b = row >> 8;
    const int i = row & 255;
    float v0 = 0.f, v1 = 0.f, v2 = 0.f, v3 = 0.f;
    #pragma unroll
    for (int s = 0; s < SPLITK; ++s) {
        const float* p = part + ((size_t)(s * BB + b) * CC + i) * CC;
        v0 += p[l]; v1 += p[l + 64]; v2 += p[l + 128]; v3 += p[l + 192];
    }
    float m = fmaxf(fmaxf(v0, v1), fmaxf(v2, v3));
    for (int off = 32; off >= 1; off >>= 1) m = fmaxf(m, __shfl_xor(m, off, 64));
    v0 = __expf(v0 - m); v1 = __expf(v1 - m); v2 = __expf(v2 - m); v3 = __expf(v3 - m);
    float s = v0 + v1 + v2 + v3;
    for (int off = 32; off >= 1; off >>= 1) s += __shfl_xor(s, off, 64);
    float rs = 1.0f / s;
    unsigned short* o = attnT + (size_t)b * CC * CC + i;   // attnT[b][j][i]
    o[(size_t)(l +   0) * CC] = f2bf(v0 * rs);
    o[(size_t)(l +  64) * CC] = f2bf(v1 * rs);
    o[(size_t)(l + 128) * CC] = f2bf(v2 * rs);
    o[(size_t)(l + 192) * CC] = f2bf(v3 * rs);
}

// ---------------- K3: out = gamma * (a · attn) + x ----------------------
// Block tile: 64 n-rows x ALL 256 j. grid (64, BB) = 1024 blocks.
// x staged exactly once (k-loop unions to the full row panel).
__global__ __launch_bounds__(256) void k_gemm2(const float* __restrict__ x,
                                               const unsigned short* __restrict__ attnT,
                                               const float* __restrict__ gamma,
                                               float* __restrict__ out) {
    __shared__ unsigned short At[64 * 72];    // [n_local][k]
    __shared__ unsigned short Bt[256 * 72];   // [j][k]
    const int n0 = blockIdx.x * 64;
    const int b  = blockIdx.y;
    const int t  = threadIdx.x;
    const int w  = t >> 6, l = t & 63;
    const int lk = (l >> 4) * 8, lm = l & 15;
    const int sc = t >> 4, sk = (t & 15) * 4;

    const float*          Abase = x + ((size_t)b * NN + n0) * CC;
    const unsigned short* Bbase = attnT + (size_t)b * CC * CC;

    floatx4 acc[4][4] = {};
    for (int k0 = 0; k0 < CC; k0 += 64) {
        #pragma unroll
        for (int r = 0; r < 4; ++r) {
            int n = sc + 16 * r;
            floatx4 av = *(const floatx4*)(Abase + (size_t)n * CC + k0 + sk);
            *(short4v*)&At[n * 72 + sk] = cvt4(av);
        }
        #pragma unroll
        for (int r = 0; r < 16; ++r) {
            int j = sc + 16 * r;
            *(short4v*)&Bt[j * 72 + sk] = *(const short4v*)(Bbase + (size_t)j * CC + k0 + sk);
        }
        __syncthreads();
        #pragma unroll
        for (int ks = 0; ks < 64; ks += 32) {
            short8v af[4], bf[4];
            #pragma unroll
            for (int mt = 0; mt < 4; ++mt)
                af[mt] = *(const short8v*)&At[(mt * 16 + lm) * 72 + ks + lk];
            #pragma unroll
            for (int nt = 0; nt < 4; ++nt)
                bf[nt] = *(const short8v*)&Bt[(w * 64 + nt * 16 + lm) * 72 + ks + lk];
            #pragma unroll
            for (int mt = 0; mt < 4; ++mt)
                #pragma unroll
                for (int nt = 0; nt < 4; ++nt)
                    acc[mt][nt] = __builtin_amdgcn_mfma_f32_16x16x32_bf16(af[mt], bf[nt], acc[mt][nt], 0, 0, 0);
        }
        __syncthreads();
    }
    const float g = gamma[0];
    const int orow = (l >> 4) * 4;
    #pragma unroll
    for (int mt = 0; mt < 4; ++mt)
        #pragma unroll
        for (int nt = 0; nt < 4; ++nt)
            #pragma unroll
            for (int r = 0; r < 4; ++r) {
                int nr = n0 + mt * 16 + orow + r;
                int j  = w * 64 + nt * 16 + lm;
                size_t idx = ((size_t)b * NN + nr) * CC + j;
                out[idx] = g * acc[mt][nt][r] + x[idx];
            }
}

extern "C" void kernel_launch(void* const* d_in, const int* in_sizes, int n_in,
                              void* d_out, int out_size, void* d_ws, size_t ws_size,
                              hipStream_t stream) {
    const float* x     = (const float*)d_in[0];
    const float* gamma = (const float*)d_in[1];
    float* out = (float*)d_out;

    char* ws = (char*)d_ws;
    unsigned short* aT    = (unsigned short*)ws;                          // 32 MB
    float*          part  = (float*)(ws + (size_t)BB * CC * NN * 2);      // 8*16*256*256*4 = 32 MB
    unsigned short* attnT = (unsigned short*)(ws + (size_t)BB * CC * NN * 2
                                                 + (size_t)SPLITK * BB * CC * CC * 4);  // 2 MB

    k_transpose<<<dim3(NN / 64, CC / 64, BB), 256, 0, stream>>>(x, aT);
    k_gemm1   <<<dim3(CC / 64, BB, SPLITK),   256, 0, stream>>>(aT, part);
    k_softmax <<<dim3(BB * CC / 4),           256, 0, stream>>>(part, attnT);
    k_gemm2   <<<dim3(NN / 64, BB),           256, 0, stream>>>(x, attnT, gamma, out);
}